// Round 3
// baseline (783.515 us; speedup 1.0000x reference)
//
#include <hip/hip_runtime.h>

typedef __attribute__((ext_vector_type(8))) short short8;
typedef __attribute__((ext_vector_type(4))) float f32x4;
typedef unsigned int u32;

#define ROW_B 1056          // 66 w-chunks * 16 B (8 bf16 channels per chunk); 64 written, 2 garbage overread
#define SLOT_B 10560        // 10 h-rows per d-plane
#define NSLOT 4

__device__ __forceinline__ unsigned short f2bf(float f) {
  unsigned u = __builtin_bit_cast(unsigned, f);
  u += 0x7FFFu + ((u >> 16) & 1u);          // RNE (inputs finite)
  return (unsigned short)(u >> 16);
}
__device__ __forceinline__ u32 cvtpk(float lo, float hi) {
  u32 r;
  asm("v_cvt_pk_bf16_f32 %0, %1, %2" : "=v"(r) : "v"(lo), "v"(hi));
  return r;
}

#define MF(ACC, H, FR, KD, KH)                                                \
  ACC[H][wt] = __builtin_amdgcn_mfma_f32_16x16x32_bf16(FR, bfragB[KD][KH],    \
                                                       ACC[H][wt], 0, 0, 0)
#define MFI(ACC, H, FR)                                                       \
  ACC[H][wt] = __builtin_amdgcn_mfma_f32_16x16x32_bf16(FR, bfragB[0][0],      \
                                                       zf4, 0, 0, 0)

// iter dp: issue loads(dp+3)->LB ; compute plane dp (slot dp&3) ; cvt+write(dp+2)
// from WB (loaded at iter dp-1 -> one full iteration of HBM-latency hiding) ;
// barrier. AN = gen(dp) opened via C=0 MFMA; AM=gen(dp-1) kd=1; AO=gen(dp-2)
// kd=2, closed (maxpool) after the barrier.
#define PROC(DP, AN, AM, AO, K1, K2, DOCLOSE, SAVEP, LB, WB)                  \
  {                                                                           \
    constexpr int dp_ = (DP);                                                 \
    if (dp_ + 3 <= 31) stage_load(dp_ + 3, LB);                               \
    const int sb_ = (dp_ & 3) * SLOT_B + rowbase;                             \
    _Pragma("unroll") for (int wt = 0; wt < 4; ++wt) {                        \
      const short8 f0 = *(const short8*)(smem + sb_ + 0 * ROW_B + physoff[wt]); \
      const short8 f1 = *(const short8*)(smem + sb_ + 1 * ROW_B + physoff[wt]); \
      const short8 f2 = *(const short8*)(smem + sb_ + 2 * ROW_B + physoff[wt]); \
      const short8 f3 = *(const short8*)(smem + sb_ + 3 * ROW_B + physoff[wt]); \
      MFI(AN, 0, f0); MFI(AN, 1, f1);                                         \
      MF(AN, 0, f1, 0, 1); MF(AN, 1, f2, 0, 1);                               \
      MF(AN, 0, f2, 0, 2); MF(AN, 1, f3, 0, 2);                               \
      if (K1) {                                                               \
        MF(AM, 0, f0, 1, 0); MF(AM, 1, f1, 1, 0);                             \
        MF(AM, 0, f1, 1, 1); MF(AM, 1, f2, 1, 1);                             \
        MF(AM, 0, f2, 1, 2); MF(AM, 1, f3, 1, 2);                             \
      }                                                                       \
      if (K2) {                                                               \
        MF(AO, 0, f0, 2, 0); MF(AO, 1, f1, 2, 0);                             \
        MF(AO, 0, f1, 2, 1); MF(AO, 1, f2, 2, 1);                             \
        MF(AO, 0, f2, 2, 2); MF(AO, 1, f3, 2, 2);                             \
      }                                                                       \
    }                                                                         \
    if (dp_ + 2 <= 31) stage_write(dp_ + 2, WB);                              \
    __syncthreads();                                                          \
    if (DOCLOSE) {                                                            \
      _Pragma("unroll") for (int wt = 0; wt < 4; ++wt) {                      \
        const float e01 = fmaxf(fmaxf(AO[0][wt][0], AO[0][wt][1]),            \
                                fmaxf(AO[1][wt][0], AO[1][wt][1]));           \
        const float e23 = fmaxf(fmaxf(AO[0][wt][2], AO[0][wt][3]),            \
                                fmaxf(AO[1][wt][2], AO[1][wt][3]));           \
        if (SAVEP) {                                                          \
          p01[wt] = e01; p23[wt] = e23;                                       \
        } else if (hvalid) {                                                  \
          sum += fmaxf(p01[wt], e01);                                         \
          if (!(wt == 3 && g == 3)) sum += fmaxf(p23[wt], e23);               \
        }                                                                     \
      }                                                                       \
    }                                                                         \
  }

// grid: 512 = 64 b * 8 h-octets ; block: 256 (4 waves x 2 h'-rows each)
__launch_bounds__(256, 2)
__global__ void conv_fused(const float* __restrict__ x,
                           const float* __restrict__ cw,
                           float* __restrict__ ws) {
  __shared__ __align__(16) unsigned char smem[NSLOT * SLOT_B];
  __shared__ float wsum[4];

  const int bid = blockIdx.x;
  const int b   = bid >> 3;
  const int hq  = bid & 7;
  const int h0  = hq * 8;

  const int tid  = threadIdx.x;
  const int lane = tid & 63;
  const int wid  = tid >> 6;
  const int nm   = lane & 15;
  const int g    = lane >> 4;

  const float* xb = x + (size_t)b * (8u * 32u * 64u * 64u);

  // ---- B fragments: 9 (kd,kh) weight-sets, K = kw*8 + c (24 used, 8 pad) ----
  short8 bfragB[3][3];
#pragma unroll
  for (int kd = 0; kd < 3; ++kd)
#pragma unroll
    for (int kh = 0; kh < 3; ++kh) {
      short8 f;
#pragma unroll
      for (int j = 0; j < 8; ++j) {
        float v = (g < 3) ? cw[(nm * 8 + j) * 27 + kd * 9 + kh * 3 + g] : 0.f;
        f[j] = (short)f2bf(v);
      }
      bfragB[kd][kh] = f;
    }

  // ---- A-fragment chunk offsets (linear; reads are bank-free by pigeonhole) ----
  const int gc = (g < 3) ? g : 2;     // pad lanes read real data, weight = 0
  int physoff[4];
#pragma unroll
  for (int wt = 0; wt < 4; ++wt) physoff[wt] = (wt * 16 + nm + gc) * 16;
  const int rowbase = (2 * wid) * ROW_B;

  // ---- staging: slot s = row*64 + w ; thread gathers 8 channels, writes b128 ----
  bool st_act[3]; const float* st_base[3]; int st_off[3];
#pragma unroll
  for (int pass = 0; pass < 3; ++pass) {
    const int t = tid + pass * 256;
    bool act = (t < 640);
    int row = (t >> 6) % 10;
    const int w = t & 63;
    int h = h0 + row;
    if (h > 63) { act = false; h = 63; }
    st_act[pass]  = act;
    st_base[pass] = xb + h * 64 + w;           // channel 0, plane 0
    st_off[pass]  = row * ROW_B + w * 16;
  }

  float ldA[3][8], ldB[3][8];

  auto stage_load = [&](int p, float (&L)[3][8]) {
#pragma unroll
    for (int pass = 0; pass < 3; ++pass) {
      if (st_act[pass]) {
        const float* sp = st_base[pass] + p * 4096;
#pragma unroll
        for (int c = 0; c < 8; ++c) L[pass][c] = sp[(size_t)c * 131072];
      }
    }
  };
  auto stage_write = [&](int p, float (&L)[3][8]) {
    unsigned char* d = smem + (p & 3) * SLOT_B;
#pragma unroll
    for (int pass = 0; pass < 3; ++pass) {
      if (st_act[pass]) {
        uint4 v;
        v.x = cvtpk(L[pass][0], L[pass][1]);
        v.y = cvtpk(L[pass][2], L[pass][3]);
        v.z = cvtpk(L[pass][4], L[pass][5]);
        v.w = cvtpk(L[pass][6], L[pass][7]);
        *(uint4*)(d + st_off[pass]) = v;
      }
    }
  };

  const bool hvalid = !(hq == 7 && wid == 3);  // h' 62,63 invalid
  const f32x4 zf4 = {0.f, 0.f, 0.f, 0.f};
  float sum = 0.f;
  float p01[4], p23[4];
  f32x4 accA[2][4], accB[2][4], accC[2][4];    // d' % 3 rotation

  // prologue: planes 0,1 staged synchronously; plane-2 loads in flight
  stage_load(0, ldA); stage_write(0, ldA);
  stage_load(1, ldB); stage_write(1, ldB);
  stage_load(2, ldA);
  __syncthreads();

  PROC(0, accA, accB, accC, 0, 0, 0, 0, ldB, ldA)
  PROC(1, accB, accA, accC, 1, 0, 0, 0, ldA, ldB)

  // main: planes 2..31, closures d' = 0..29 (even=save, odd=combine)
  for (int i = 0; i < 5; ++i) {
    const int p0 = 2 + 6 * i;
    switch (p0) {
      case 2:
        PROC(2, accC, accB, accA, 1, 1, 1, 1, ldB, ldA)
        PROC(3, accA, accC, accB, 1, 1, 1, 0, ldA, ldB)
        PROC(4, accB, accA, accC, 1, 1, 1, 1, ldB, ldA)
        PROC(5, accC, accB, accA, 1, 1, 1, 0, ldA, ldB)
        PROC(6, accA, accC, accB, 1, 1, 1, 1, ldB, ldA)
        PROC(7, accB, accA, accC, 1, 1, 1, 0, ldA, ldB)
        break;
      case 8:
        PROC(8, accC, accB, accA, 1, 1, 1, 1, ldB, ldA)
        PROC(9, accA, accC, accB, 1, 1, 1, 0, ldA, ldB)
        PROC(10, accB, accA, accC, 1, 1, 1, 1, ldB, ldA)
        PROC(11, accC, accB, accA, 1, 1, 1, 0, ldA, ldB)
        PROC(12, accA, accC, accB, 1, 1, 1, 1, ldB, ldA)
        PROC(13, accB, accA, accC, 1, 1, 1, 0, ldA, ldB)
        break;
      case 14:
        PROC(14, accC, accB, accA, 1, 1, 1, 1, ldB, ldA)
        PROC(15, accA, accC, accB, 1, 1, 1, 0, ldA, ldB)
        PROC(16, accB, accA, accC, 1, 1, 1, 1, ldB, ldA)
        PROC(17, accC, accB, accA, 1, 1, 1, 0, ldA, ldB)
        PROC(18, accA, accC, accB, 1, 1, 1, 1, ldB, ldA)
        PROC(19, accB, accA, accC, 1, 1, 1, 0, ldA, ldB)
        break;
      case 20:
        PROC(20, accC, accB, accA, 1, 1, 1, 1, ldB, ldA)
        PROC(21, accA, accC, accB, 1, 1, 1, 0, ldA, ldB)
        PROC(22, accB, accA, accC, 1, 1, 1, 1, ldB, ldA)
        PROC(23, accC, accB, accA, 1, 1, 1, 0, ldA, ldB)
        PROC(24, accA, accC, accB, 1, 1, 1, 1, ldB, ldA)
        PROC(25, accB, accA, accC, 1, 1, 1, 0, ldA, ldB)
        break;
      default:
        PROC(26, accC, accB, accA, 1, 1, 1, 1, ldB, ldA)
        PROC(27, accA, accC, accB, 1, 1, 1, 0, ldA, ldB)
        PROC(28, accB, accA, accC, 1, 1, 1, 1, ldB, ldA)
        PROC(29, accC, accB, accA, 1, 1, 1, 0, ldA, ldB)
        PROC(30, accA, accC, accB, 1, 1, 1, 1, ldB, ldA)
        PROC(31, accB, accA, accC, 1, 1, 1, 0, ldA, ldB)
        break;
    }
  }

  // block reduce -> one partial per block
#pragma unroll
  for (int off = 32; off > 0; off >>= 1) sum += __shfl_down(sum, off);
  if (lane == 0) wsum[wid] = sum;
  __syncthreads();
  if (tid == 0) ws[bid] = wsum[0] + wsum[1] + wsum[2] + wsum[3];
}

// out[b] = 0.5 * S_b / 14415 + 0.5 * sum(conv_bias) + sum(bias)
__global__ void finalize_k(const float* __restrict__ ws,
                           const float* __restrict__ cb,
                           const float* __restrict__ bias,
                           float* __restrict__ out) {
  const int b = threadIdx.x;
  float s = 0.f;
#pragma unroll
  for (int hq = 0; hq < 8; ++hq) s += ws[b * 8 + hq];
  float cbs = 0.f, bs = 0.f;
#pragma unroll
  for (int c = 0; c < 16; ++c) { cbs += cb[c]; bs += bias[c]; }
  out[b] = 0.5f * s / 14415.f + 0.5f * cbs + bs;
}

extern "C" void kernel_launch(void* const* d_in, const int* in_sizes, int n_in,
                              void* d_out, int out_size, void* d_ws, size_t ws_size,
                              hipStream_t stream) {
  const float* x    = (const float*)d_in[0];
  const float* cw   = (const float*)d_in[1];
  const float* cb   = (const float*)d_in[2];
  const float* bias = (const float*)d_in[3];
  float* out = (float*)d_out;
  float* ws  = (float*)d_ws;   // 512 floats

  hipLaunchKernelGGL(conv_fused, dim3(512), dim3(256), 0, stream, x, cw, ws);
  hipLaunchKernelGGL(finalize_k, dim3(1), dim3(64), 0, stream, ws, cb, bias, out);
}

// Round 4
// 75.275 us; speedup vs baseline: 10.4087x; 10.4087x over previous
//
#include <hip/hip_runtime.h>

typedef __attribute__((ext_vector_type(8))) short short8;
typedef __attribute__((ext_vector_type(4))) float f32x4;
typedef unsigned int u32;

#define ROW_B 1056          // 66 w-chunks * 16 B (8 bf16 channels per chunk); 64 written, 2 pad
#define SLOT_B 10560        // 10 h-rows per d-plane
#define NSLOT 4

__device__ __forceinline__ unsigned short f2bf(float f) {
  unsigned u = __builtin_bit_cast(unsigned, f);
  u += 0x7FFFu + ((u >> 16) & 1u);          // RNE (inputs finite)
  return (unsigned short)(u >> 16);
}
__device__ __forceinline__ u32 cvtpk(float lo, float hi) {
  u32 r;
  asm("v_cvt_pk_bf16_f32 %0, %1, %2" : "=v"(r) : "v"(lo), "v"(hi));
  return r;
}

#define MF(ACC, H, FR, KD, KH)                                                \
  ACC[H][wt] = __builtin_amdgcn_mfma_f32_16x16x32_bf16(FR, bfragB[KD][KH],    \
                                                       ACC[H][wt], 0, 0, 0)
#define MFI(ACC, H, FR)                                                       \
  ACC[H][wt] = __builtin_amdgcn_mfma_f32_16x16x32_bf16(FR, bfragB[0][0],      \
                                                       zf4, 0, 0, 0)

// iter dp: issue global loads for plane dp+2 (hidden under this iter's MFMAs),
// compute plane dp from LDS slot dp&3, cvt+write plane dp+2 to slot (dp+2)&3,
// barrier, then close gen dp-2 (maxpool+reduce, registers only).
// AN = gen(dp) opened via C=0 MFMA; AM = gen(dp-1) kd=1; AO = gen(dp-2) kd=2.
#define PROC(DP, AN, AM, AO, K1, K2, DOCLOSE, SAVEP, DOSTAGE)                 \
  {                                                                           \
    const int dp_ = (DP);                                                     \
    if (DOSTAGE) {                                                            \
      stage_load(dp_ + 2);                                                    \
      __builtin_amdgcn_sched_barrier(0);  /* pin loads before MFMA phase */   \
    }                                                                         \
    const int sb_ = (dp_ & 3) * SLOT_B + rowbase;                             \
    __builtin_amdgcn_s_setprio(1);                                            \
    _Pragma("unroll") for (int wt = 0; wt < 4; ++wt) {                        \
      const short8 f0 = *(const short8*)(smem + sb_ + 0 * ROW_B + physoff[wt]); \
      const short8 f1 = *(const short8*)(smem + sb_ + 1 * ROW_B + physoff[wt]); \
      const short8 f2 = *(const short8*)(smem + sb_ + 2 * ROW_B + physoff[wt]); \
      const short8 f3 = *(const short8*)(smem + sb_ + 3 * ROW_B + physoff[wt]); \
      MFI(AN, 0, f0); MFI(AN, 1, f1);                                         \
      MF(AN, 0, f1, 0, 1); MF(AN, 1, f2, 0, 1);                               \
      MF(AN, 0, f2, 0, 2); MF(AN, 1, f3, 0, 2);                               \
      if (K1) {                                                               \
        MF(AM, 0, f0, 1, 0); MF(AM, 1, f1, 1, 0);                             \
        MF(AM, 0, f1, 1, 1); MF(AM, 1, f2, 1, 1);                             \
        MF(AM, 0, f2, 1, 2); MF(AM, 1, f3, 1, 2);                             \
      }                                                                       \
      if (K2) {                                                               \
        MF(AO, 0, f0, 2, 0); MF(AO, 1, f1, 2, 0);                             \
        MF(AO, 0, f1, 2, 1); MF(AO, 1, f2, 2, 1);                             \
        MF(AO, 0, f2, 2, 2); MF(AO, 1, f3, 2, 2);                             \
      }                                                                       \
    }                                                                         \
    __builtin_amdgcn_s_setprio(0);                                            \
    if (DOSTAGE) stage_write(dp_ + 2);                                        \
    __syncthreads();                                                          \
    if (DOCLOSE) {                                                            \
      _Pragma("unroll") for (int wt = 0; wt < 4; ++wt) {                      \
        const float e01 = fmaxf(fmaxf(AO[0][wt][0], AO[0][wt][1]),            \
                                fmaxf(AO[1][wt][0], AO[1][wt][1]));           \
        const float e23 = fmaxf(fmaxf(AO[0][wt][2], AO[0][wt][3]),            \
                                fmaxf(AO[1][wt][2], AO[1][wt][3]));           \
        if (SAVEP) {                                                          \
          p01[wt] = e01; p23[wt] = e23;                                       \
        } else if (hvalid) {                                                  \
          sum += fmaxf(p01[wt], e01);                                         \
          if (!(wt == 3 && g == 3)) sum += fmaxf(p23[wt], e23);               \
        }                                                                     \
      }                                                                       \
    }                                                                         \
  }

// grid: 512 = 64 b * 8 h-octets ; block: 256 (4 waves x 2 h'-rows each)
__launch_bounds__(256, 2)
__global__ void conv_fused(const float* __restrict__ x,
                           const float* __restrict__ cw,
                           float* __restrict__ ws) {
  __shared__ __align__(16) unsigned char smem[NSLOT * SLOT_B];
  __shared__ float wsum[4];

  const int bid = blockIdx.x;
  const int b   = bid >> 3;
  const int hq  = bid & 7;
  const int h0  = hq * 8;

  const int tid  = threadIdx.x;
  const int lane = tid & 63;
  const int wid  = tid >> 6;
  const int nm   = lane & 15;
  const int g    = lane >> 4;

  const float* xb = x + (size_t)b * (8u * 32u * 64u * 64u);

  // ---- B fragments: 9 (kd,kh) weight-sets, K = kw*8 + c (24 used, 8 pad) ----
  short8 bfragB[3][3];
#pragma unroll
  for (int kd = 0; kd < 3; ++kd)
#pragma unroll
    for (int kh = 0; kh < 3; ++kh) {
      short8 f;
#pragma unroll
      for (int j = 0; j < 8; ++j) {
        float v = (g < 3) ? cw[(nm * 8 + j) * 27 + kd * 9 + kh * 3 + g] : 0.f;
        f[j] = (short)f2bf(v);
      }
      bfragB[kd][kh] = f;
    }

  // ---- A-fragment chunk offsets (reads are bank-conflict-free by pigeonhole) ----
  const int gc = (g < 3) ? g : 2;     // pad lanes read real data, weight = 0
  int physoff[4];
#pragma unroll
  for (int wt = 0; wt < 4; ++wt) physoff[wt] = (wt * 16 + nm + gc) * 16;
  const int rowbase = (2 * wid) * ROW_B;

  // ---- staging: slot s = row*64 + w ; thread gathers 8 channels, one b128 write ----
  bool st_act[3]; const float* st_base[3]; int st_off[3];
#pragma unroll
  for (int pass = 0; pass < 3; ++pass) {
    const int t = tid + pass * 256;
    bool act = (t < 640);
    int row = (t >> 6) % 10;
    const int w = t & 63;
    int h = h0 + row;
    if (h > 63) { act = false; h = 63; }
    st_act[pass]  = act;
    st_base[pass] = xb + h * 64 + w;           // channel 0, plane 0
    st_off[pass]  = row * ROW_B + w * 16;
  }

  float ld[3][8];   // single in-flight staging buffer (24 VGPRs)

  auto stage_load = [&](int p) {
#pragma unroll
    for (int pass = 0; pass < 3; ++pass) {
      if (st_act[pass]) {
        const float* sp = st_base[pass] + p * 4096;
#pragma unroll
        for (int c = 0; c < 8; ++c) ld[pass][c] = sp[(size_t)c * 131072];
      }
    }
  };
  auto stage_write = [&](int p) {
    unsigned char* d = smem + (p & 3) * SLOT_B;
#pragma unroll
    for (int pass = 0; pass < 3; ++pass) {
      if (st_act[pass]) {
        uint4 v;
        v.x = cvtpk(ld[pass][0], ld[pass][1]);
        v.y = cvtpk(ld[pass][2], ld[pass][3]);
        v.z = cvtpk(ld[pass][4], ld[pass][5]);
        v.w = cvtpk(ld[pass][6], ld[pass][7]);
        *(uint4*)(d + st_off[pass]) = v;
      }
    }
  };

  const bool hvalid = !(hq == 7 && wid == 3);  // h' 62,63 invalid
  const f32x4 zf4 = {0.f, 0.f, 0.f, 0.f};
  float sum = 0.f;
  float p01[4], p23[4];
  f32x4 accA[2][4], accB[2][4], accC[2][4];    // gen % 3 rotation

  // prologue: planes 0,1 staged synchronously
  stage_load(0); stage_write(0);
  stage_load(1); stage_write(1);
  __syncthreads();

  PROC(0, accA, accB, accC, 0, 0, 0, 0, 1)
  PROC(1, accB, accA, accC, 1, 0, 0, 0, 1)

  // main: dp = 2..25 in a compact period-6 loop (runtime slot index)
  for (int p0 = 2; p0 <= 20; p0 += 6) {
    PROC(p0 + 0, accC, accB, accA, 1, 1, 1, 1, 1)
    PROC(p0 + 1, accA, accC, accB, 1, 1, 1, 0, 1)
    PROC(p0 + 2, accB, accA, accC, 1, 1, 1, 1, 1)
    PROC(p0 + 3, accC, accB, accA, 1, 1, 1, 0, 1)
    PROC(p0 + 4, accA, accC, accB, 1, 1, 1, 1, 1)
    PROC(p0 + 5, accB, accA, accC, 1, 1, 1, 0, 1)
  }
  // epilogue: dp = 26..31 (staging stops after plane 31)
  PROC(26, accC, accB, accA, 1, 1, 1, 1, 1)
  PROC(27, accA, accC, accB, 1, 1, 1, 0, 1)
  PROC(28, accB, accA, accC, 1, 1, 1, 1, 1)
  PROC(29, accC, accB, accA, 1, 1, 1, 0, 1)
  PROC(30, accA, accC, accB, 1, 1, 1, 1, 0)
  PROC(31, accB, accA, accC, 1, 1, 1, 0, 0)

  // block reduce -> one partial per block
#pragma unroll
  for (int off = 32; off > 0; off >>= 1) sum += __shfl_down(sum, off);
  if (lane == 0) wsum[wid] = sum;
  __syncthreads();
  if (tid == 0) ws[bid] = wsum[0] + wsum[1] + wsum[2] + wsum[3];
}

// out[b] = 0.5 * S_b / 14415 + 0.5 * sum(conv_bias) + sum(bias)
__global__ void finalize_k(const float* __restrict__ ws,
                           const float* __restrict__ cb,
                           const float* __restrict__ bias,
                           float* __restrict__ out) {
  const int b = threadIdx.x;
  float s = 0.f;
#pragma unroll
  for (int hq = 0; hq < 8; ++hq) s += ws[b * 8 + hq];
  float cbs = 0.f, bs = 0.f;
#pragma unroll
  for (int c = 0; c < 16; ++c) { cbs += cb[c]; bs += bias[c]; }
  out[b] = 0.5f * s / 14415.f + 0.5f * cbs + bs;
}

extern "C" void kernel_launch(void* const* d_in, const int* in_sizes, int n_in,
                              void* d_out, int out_size, void* d_ws, size_t ws_size,
                              hipStream_t stream) {
  const float* x    = (const float*)d_in[0];
  const float* cw   = (const float*)d_in[1];
  const float* cb   = (const float*)d_in[2];
  const float* bias = (const float*)d_in[3];
  float* out = (float*)d_out;
  float* ws  = (float*)d_ws;   // 512 floats

  hipLaunchKernelGGL(conv_fused, dim3(512), dim3(256), 0, stream, x, cw, ws);
  hipLaunchKernelGGL(finalize_k, dim3(1), dim3(64), 0, stream, ws, cb, bias, out);
}